// Round 10
// baseline (195.968 us; speedup 1.0000x reference)
//
#include <hip/hip_runtime.h>
#include <cstddef>

namespace {
constexpr int Bn = 4, Fn = 32, Cn = 4096, Tn = 32, En = 65536, Kw = 9;
constexpr int PLANE = Tn * Fn;   // 1024 elems per (b,c) plane
}

typedef __attribute__((ext_vector_type(8))) short bf16x8;
typedef __attribute__((ext_vector_type(4))) float f32x4;
typedef __attribute__((ext_vector_type(4))) unsigned int u32x4;

static __device__ __forceinline__ unsigned short f2bf(float f) {
    unsigned int u = __float_as_uint(f);
    unsigned int r = (u + 0x7fffu + ((u >> 16) & 1u)) >> 16;
    return (unsigned short)r;
}
// unpack uint (2 bf16) -> 2 floats: lo = u<<16, hi = u & 0xffff0000
static __device__ __forceinline__ float bflo(unsigned u) { return __uint_as_float(u << 16); }
static __device__ __forceinline__ float bfhi(unsigned u) { return __uint_as_float(u & 0xffff0000u); }

// ---------------- init (deg=1, hist=cnt=0, stats=0) + conv-weight fragments ----------------
__global__ __launch_bounds__(256) void k_init(float* deg, int* hist, int* cnt,
                                              float* s1, float* q1, float* s2, float* q2,
                                              const float* __restrict__ cw,
                                              ushort* __restrict__ wfrag) {
    int i = blockIdx.x * 256 + threadIdx.x;
    if (i < Cn) { deg[i] = 1.0f; hist[i] = 0; cnt[i] = 0; }
    if (i < Bn * Fn) { s1[i] = 0.f; q1[i] = 0.f; s2[i] = 0.f; q2[i] = 0.f; }
    if (i < 2 * 9 * 64) {
        int l  = i & 63;
        int k  = (i >> 6) % 9;
        int nt = i / 576;
        int o  = nt * 16 + (l & 15);
        int ib = (l >> 4) * 8;
        ushort v[8];
        #pragma unroll
        for (int j = 0; j < 8; ++j) v[j] = f2bf(cw[o * 288 + (ib + j) * 9 + k]);
        uint4 pk;
        pk.x = (unsigned)v[0] | ((unsigned)v[1] << 16);
        pk.y = (unsigned)v[2] | ((unsigned)v[3] << 16);
        pk.z = (unsigned)v[4] | ((unsigned)v[5] << 16);
        pk.w = (unsigned)v[6] | ((unsigned)v[7] << 16);
        ((uint4*)wfrag)[i] = pk;
    }
}

// ---------------- degree + dst histogram ----------------
__global__ __launch_bounds__(256) void k_deg(const int* ei, const float* ew, float* deg, int* hist) {
    int e = blockIdx.x * 256 + threadIdx.x;
    int d = ei[En + e];
    atomicAdd(&deg[d], ew[e]);
    atomicAdd(&hist[d], 1);
}

// ---------------- exclusive scan of hist (C=4096, one block) ----------------
__global__ __launch_bounds__(1024) void k_scan(const int* hist, int* ptr) {
    __shared__ int part[1024];
    int tid = threadIdx.x;
    int v0 = hist[tid*4+0], v1 = hist[tid*4+1], v2 = hist[tid*4+2], v3 = hist[tid*4+3];
    int tot = v0 + v1 + v2 + v3;
    part[tid] = tot;
    __syncthreads();
    for (int off = 1; off < 1024; off <<= 1) {
        int add = (tid >= off) ? part[tid - off] : 0;
        __syncthreads();
        part[tid] += add;
        __syncthreads();
    }
    int run = part[tid] - tot;  // exclusive base
    ptr[tid*4+0] = run; run += v0;
    ptr[tid*4+1] = run; run += v1;
    ptr[tid*4+2] = run; run += v2;
    ptr[tid*4+3] = run; run += v3;
    if (tid == 1023) ptr[4096] = run;
}

// ---------------- CSR fill (sorted by dst) with fused norm ----------------
__global__ __launch_bounds__(256) void k_fill(const int* ei, const float* ew, const float* deg,
                                              const int* ptr, int* cnt, int* csrs, float* csrw) {
    int e = blockIdx.x * 256 + threadIdx.x;
    int s = ei[e];
    int d = ei[En + e];
    float w = rsqrtf(deg[s]) * ew[e] * rsqrtf(deg[d]);
    int pos = ptr[d] + atomicAdd(&cnt[d], 1);
    csrs[pos] = s;
    csrw[pos] = w;
}

// ---------------- x_lin[b][c][t][g] (bf16) = sum_f x[b,f,c,t] * W[f,g] ----------------
__global__ __launch_bounds__(256) void k_xlin(const float* __restrict__ x,
                                              const float* __restrict__ W,
                                              ushort* __restrict__ bufA) {
    __shared__ float wl[Fn * Fn];
    int tid = threadIdx.x;
    ((float4*)wl)[tid] = ((const float4*)W)[tid];
    int b  = blockIdx.x >> 9;           // / 512
    int c0 = (blockIdx.x & 511) << 3;   // 8 nodes per block
    __syncthreads();

    float acc[Fn];
    #pragma unroll
    for (int g = 0; g < Fn; ++g) acc[g] = 0.f;

    const float* xp = x + (size_t)b * Fn * Cn * Tn + (size_t)c0 * Tn + tid;
    #pragma unroll
    for (int f = 0; f < Fn; ++f) {
        float xv = xp[(size_t)f * Cn * Tn];
        #pragma unroll
        for (int g = 0; g < Fn; ++g) acc[g] += xv * wl[f * Fn + g];
    }
    ushort* op = bufA + (size_t)(b * Cn + c0) * PLANE + tid * Fn;
    #pragma unroll
    for (int g8 = 0; g8 < 4; ++g8) {
        uint4 pk;
        pk.x = (unsigned)f2bf(acc[g8*8+0]) | ((unsigned)f2bf(acc[g8*8+1]) << 16);
        pk.y = (unsigned)f2bf(acc[g8*8+2]) | ((unsigned)f2bf(acc[g8*8+3]) << 16);
        pk.z = (unsigned)f2bf(acc[g8*8+4]) | ((unsigned)f2bf(acc[g8*8+5]) << 16);
        pk.w = (unsigned)f2bf(acc[g8*8+6]) | ((unsigned)f2bf(acc[g8*8+7]) << 16);
        ((uint4*)op)[g8] = pk;
    }
}

// ---------------- GCN aggregation, XCD-L2-tiled SpMM ----------------
// One wave = one node; edge indices wave-uniform -> SGPR (readfirstlane) so
// gathers are saddr-form. bufB stores are non-temporal (bypass L2) to keep
// the 4 MB gather pool resident per XCD.
__global__ __launch_bounds__(256) void k_agg(const ushort* __restrict__ bufA,
                                             const float* __restrict__ deg,
                                             const int* __restrict__ ptr,
                                             const int* __restrict__ csrs,
                                             const float* __restrict__ csrw,
                                             const float* __restrict__ gb,
                                             ushort* __restrict__ bufB,
                                             float* s1, float* q1) {
    __shared__ float ssum[Fn], ssq[Fn];
    int tid = threadIdx.x;
    int tile = blockIdx.x & 7;
    int chunk = blockIdx.x >> 3;          // 1024 chunks x 4 nodes
    int b = tile >> 1, half = tile & 1;
    int wv = tid >> 6, l = tid & 63;
    int c = chunk * 4 + wv;               // one node per wave
    if (tid < Fn) { ssum[tid] = 0.f; ssq[tid] = 0.f; }

    const ushort* base = bufA + (size_t)b * Cn * PLANE + half * 512;
    ushort* obase = bufB + (size_t)b * Cn * PLANE + half * 512;
    int e0 = l * 8;                        // 8 elems per lane (16 B)
    int f0 = e0 & 31;
    float gbv[8];
    {
        float4 gA = *(const float4*)(gb + f0);
        float4 gB = *(const float4*)(gb + f0 + 4);
        gbv[0]=gA.x; gbv[1]=gA.y; gbv[2]=gA.z; gbv[3]=gA.w;
        gbv[4]=gB.x; gbv[5]=gB.y; gbv[6]=gB.z; gbv[7]=gB.w;
    }

    float a[8];
    {
        float d2 = 1.0f / deg[c];
        uint4 sv = *(const uint4*)(base + (size_t)c * PLANE + e0);
        a[0] = bflo(sv.x) * d2; a[1] = bfhi(sv.x) * d2;
        a[2] = bflo(sv.y) * d2; a[3] = bfhi(sv.y) * d2;
        a[4] = bflo(sv.z) * d2; a[5] = bfhi(sv.z) * d2;
        a[6] = bflo(sv.w) * d2; a[7] = bfhi(sv.w) * d2;
    }

#define ACC8(U, W) { \
        a[0] += bflo((U).x) * (W); a[1] += bfhi((U).x) * (W); \
        a[2] += bflo((U).y) * (W); a[3] += bfhi((U).y) * (W); \
        a[4] += bflo((U).z) * (W); a[5] += bfhi((U).z) * (W); \
        a[6] += bflo((U).w) * (W); a[7] += bfhi((U).w) * (W); }

    int j0 = ptr[c], j1 = ptr[c + 1];
    int j = j0;
    for (; j + 7 < j1; j += 8) {
        int s0 = __builtin_amdgcn_readfirstlane(csrs[j + 0]);
        int s1v= __builtin_amdgcn_readfirstlane(csrs[j + 1]);
        int s2 = __builtin_amdgcn_readfirstlane(csrs[j + 2]);
        int s3 = __builtin_amdgcn_readfirstlane(csrs[j + 3]);
        int s4 = __builtin_amdgcn_readfirstlane(csrs[j + 4]);
        int s5 = __builtin_amdgcn_readfirstlane(csrs[j + 5]);
        int s6 = __builtin_amdgcn_readfirstlane(csrs[j + 6]);
        int s7 = __builtin_amdgcn_readfirstlane(csrs[j + 7]);
        float w0 = csrw[j+0], w1 = csrw[j+1], w2 = csrw[j+2], w3 = csrw[j+3];
        float w4 = csrw[j+4], w5 = csrw[j+5], w6 = csrw[j+6], w7 = csrw[j+7];
        uint4 u0 = *(const uint4*)(base + (size_t)s0  * PLANE + e0);
        uint4 u1 = *(const uint4*)(base + (size_t)s1v * PLANE + e0);
        uint4 u2 = *(const uint4*)(base + (size_t)s2  * PLANE + e0);
        uint4 u3 = *(const uint4*)(base + (size_t)s3  * PLANE + e0);
        uint4 u4 = *(const uint4*)(base + (size_t)s4  * PLANE + e0);
        uint4 u5 = *(const uint4*)(base + (size_t)s5  * PLANE + e0);
        uint4 u6 = *(const uint4*)(base + (size_t)s6  * PLANE + e0);
        uint4 u7 = *(const uint4*)(base + (size_t)s7  * PLANE + e0);
        ACC8(u0, w0); ACC8(u1, w1); ACC8(u2, w2); ACC8(u3, w3);
        ACC8(u4, w4); ACC8(u5, w5); ACC8(u6, w6); ACC8(u7, w7);
    }
    if (j + 3 < j1) {
        int s0 = __builtin_amdgcn_readfirstlane(csrs[j + 0]);
        int s1v= __builtin_amdgcn_readfirstlane(csrs[j + 1]);
        int s2 = __builtin_amdgcn_readfirstlane(csrs[j + 2]);
        int s3 = __builtin_amdgcn_readfirstlane(csrs[j + 3]);
        float w0 = csrw[j+0], w1 = csrw[j+1], w2 = csrw[j+2], w3 = csrw[j+3];
        uint4 u0 = *(const uint4*)(base + (size_t)s0  * PLANE + e0);
        uint4 u1 = *(const uint4*)(base + (size_t)s1v * PLANE + e0);
        uint4 u2 = *(const uint4*)(base + (size_t)s2  * PLANE + e0);
        uint4 u3 = *(const uint4*)(base + (size_t)s3  * PLANE + e0);
        ACC8(u0, w0); ACC8(u1, w1); ACC8(u2, w2); ACC8(u3, w3);
        j += 4;
    }
    for (; j < j1; ++j) {
        int s0 = __builtin_amdgcn_readfirstlane(csrs[j]);
        float w0 = csrw[j];
        uint4 u0 = *(const uint4*)(base + (size_t)s0 * PLANE + e0);
        ACC8(u0, w0);
    }
#undef ACC8

    float st[8], sq[8];
    u32x4 pk;
    #pragma unroll
    for (int jj = 0; jj < 8; ++jj) {
        a[jj] += gbv[jj];
        st[jj] = a[jj]; sq[jj] = a[jj] * a[jj];
    }
    pk.x = (unsigned)f2bf(a[0]) | ((unsigned)f2bf(a[1]) << 16);
    pk.y = (unsigned)f2bf(a[2]) | ((unsigned)f2bf(a[3]) << 16);
    pk.z = (unsigned)f2bf(a[4]) | ((unsigned)f2bf(a[5]) << 16);
    pk.w = (unsigned)f2bf(a[6]) | ((unsigned)f2bf(a[7]) << 16);
    __builtin_nontemporal_store(pk, (u32x4*)(obase + (size_t)c * PLANE + e0));

    // reduce over lanes sharing f0 (xor 4,8,16,32 preserves l&3)
    #pragma unroll
    for (int jj = 0; jj < 8; ++jj) {
        #pragma unroll
        for (int d = 4; d < 64; d <<= 1) {
            st[jj] += __shfl_xor(st[jj], d);
            sq[jj] += __shfl_xor(sq[jj], d);
        }
    }
    __syncthreads();  // ssum/ssq zeroed
    if (l < 4) {
        #pragma unroll
        for (int jj = 0; jj < 8; ++jj) {
            atomicAdd(&ssum[f0 + jj], st[jj]);
            atomicAdd(&ssq[f0 + jj], sq[jj]);
        }
    }
    __syncthreads();
    if (tid < Fn) {
        atomicAdd(&s1[b * Fn + tid], ssum[tid]);
        atomicAdd(&q1[b * Fn + tid], ssq[tid]);
    }
}

// ---------------- IN1 -> ReLU -> Conv(1xK) via bf16 MFMA + IN2 stats ----------------
__global__ __launch_bounds__(256) void k_convm(const ushort* __restrict__ bufB,
                                               const float* __restrict__ s1,
                                               const float* __restrict__ q1,
                                               const ushort* __restrict__ wfrag,
                                               const float* __restrict__ cb,
                                               ushort* __restrict__ bufC,
                                               float* s2, float* q2) {
    __shared__ __align__(16) ushort zbuf[4 * 40 * 72];
    __shared__ float ssum[Fn], ssq[Fn];
    int tid = threadIdx.x;
    int l = tid & 63, w = tid >> 6;
    int b  = blockIdx.x >> 9;                 // 512 blocks per b
    int c0 = (blockIdx.x & 511) * 8 + w * 2;  // 2 planes per wave

    if (tid < Fn) { ssum[tid] = 0.f; ssq[tid] = 0.f; }

    ushort* z = zbuf + w * (40 * 72);
    if (l < 16) {  // zero pad rows 0..3 and 36..39, cols 0..31 (only ones read)
        #pragma unroll
        for (int p = 0; p < 4; ++p) {
            *(unsigned*)&z[p * 72 + l * 2] = 0u;
            *(unsigned*)&z[(36 + p) * 72 + l * 2] = 0u;
        }
    }

    // B fragments resident in VGPRs
    bf16x8 wf0[9], wf1[9];
    #pragma unroll
    for (int k = 0; k < Kw; ++k) {
        wf0[k] = *(const bf16x8*)(wfrag + ((0 * 9 + k) * 64 + l) * 8);
        wf1[k] = *(const bf16x8*)(wfrag + ((1 * 9 + k) * 64 + l) * 8);
    }
    // IN1 finalize inline: f = (l&1)*16 + j ; pm = -mu*r, pr = r
    const float invN = 1.0f / (float)(Cn * Tn);
    float pm[16], pr[16];
    {
        int fb = b * Fn + (l & 1) * 16;
        #pragma unroll
        for (int j = 0; j < 16; ++j) {
            float mu = s1[fb + j] * invN;
            float var = q1[fb + j] * invN - mu * mu;
            float r = rsqrtf(var + 1e-5f);
            pm[j] = -mu * r; pr[j] = r;
        }
    }
    float cbv0 = cb[l & 15], cbv1 = cb[16 + (l & 15)];
    __syncthreads();

    float ss0 = 0.f, ss1 = 0.f, qq0 = 0.f, qq1 = 0.f;
    const ushort* za = z + (l & 15) * 72 + (l >> 4) * 8;

    for (int p = 0; p < 2; ++p) {
        int c = c0 + p;
        // ---- build z: load bf16 plane, IN1-normalize + ReLU, back to bf16 ----
        const ushort* src = bufB + (size_t)(b * Cn + c) * PLANE + l * 16;
        uint4 i0 = *(const uint4*)(src);
        uint4 i1 = *(const uint4*)(src + 8);
        float iv[16] = { bflo(i0.x), bfhi(i0.x), bflo(i0.y), bfhi(i0.y),
                         bflo(i0.z), bfhi(i0.z), bflo(i0.w), bfhi(i0.w),
                         bflo(i1.x), bfhi(i1.x), bflo(i1.y), bfhi(i1.y),
                         bflo(i1.z), bfhi(i1.z), bflo(i1.w), bfhi(i1.w) };
        ushort tmp[16];
        #pragma unroll
        for (int j = 0; j < 16; ++j)
            tmp[j] = f2bf(fmaxf(0.f, iv[j] * pr[j] + pm[j]));
        {
            int t = l >> 1, h = l & 1;
            ushort* zw = z + (t + 4) * 72 + h * 16;
            uint4 w0, w1;
            w0.x = (unsigned)tmp[0] | ((unsigned)tmp[1] << 16);
            w0.y = (unsigned)tmp[2] | ((unsigned)tmp[3] << 16);
            w0.z = (unsigned)tmp[4] | ((unsigned)tmp[5] << 16);
            w0.w = (unsigned)tmp[6] | ((unsigned)tmp[7] << 16);
            w1.x = (unsigned)tmp[8] | ((unsigned)tmp[9] << 16);
            w1.y = (unsigned)tmp[10] | ((unsigned)tmp[11] << 16);
            w1.z = (unsigned)tmp[12] | ((unsigned)tmp[13] << 16);
            w1.w = (unsigned)tmp[14] | ((unsigned)tmp[15] << 16);
            *(uint4*)(zw) = w0;
            *(uint4*)(zw + 8) = w1;
        }
        // same-wave LDS write->read dependency: compiler inserts lgkmcnt waits

        // ---- MFMA: D[32t x 32o] = A[32t x 288] * B[288 x 32o] ----
        f32x4 acc00 = {0,0,0,0}, acc01 = {0,0,0,0}, acc10 = {0,0,0,0}, acc11 = {0,0,0,0};
        #pragma unroll
        for (int k = 0; k < Kw; ++k) {
            bf16x8 a0 = *(const bf16x8*)(za + k * 72);
            acc00 = __builtin_amdgcn_mfma_f32_16x16x32_bf16(a0, wf0[k], acc00, 0, 0, 0);
            acc01 = __builtin_amdgcn_mfma_f32_16x16x32_bf16(a0, wf1[k], acc01, 0, 0, 0);
        }
        #pragma unroll
        for (int k = 0; k < Kw; ++k) {
            bf16x8 a1 = *(const bf16x8*)(za + (16 + k) * 72);
            acc10 = __builtin_amdgcn_mfma_f32_16x16x32_bf16(a1, wf0[k], acc10, 0, 0, 0);
            acc11 = __builtin_amdgcn_mfma_f32_16x16x32_bf16(a1, wf1[k], acc11, 0, 0, 0);
        }

        // ---- epilogue: +bias, store bf16, IN2 partial stats (fp32) ----
        ushort* dst = bufC + (size_t)(b * Cn + c) * PLANE;
        int col = l & 15, r0 = (l >> 4) * 4;
        #pragma unroll
        for (int r = 0; r < 4; ++r) {
            float v00 = acc00[r] + cbv0;
            float v01 = acc01[r] + cbv1;
            float v10 = acc10[r] + cbv0;
            float v11 = acc11[r] + cbv1;
            dst[(r0 + r) * 32 + col]            = f2bf(v00);
            dst[(r0 + r) * 32 + 16 + col]       = f2bf(v01);
            dst[(16 + r0 + r) * 32 + col]       = f2bf(v10);
            dst[(16 + r0 + r) * 32 + 16 + col]  = f2bf(v11);
            ss0 += v00 + v10; qq0 += v00 * v00 + v10 * v10;
            ss1 += v01 + v11; qq1 += v01 * v01 + v11 * v11;
        }
    }

    // ---- reduce stats across the 4 lane-groups, accumulate to block LDS ----
    ss0 += __shfl_xor(ss0, 16); ss0 += __shfl_xor(ss0, 32);
    qq0 += __shfl_xor(qq0, 16); qq0 += __shfl_xor(qq0, 32);
    ss1 += __shfl_xor(ss1, 16); ss1 += __shfl_xor(ss1, 32);
    qq1 += __shfl_xor(qq1, 16); qq1 += __shfl_xor(qq1, 32);
    if ((l >> 4) == 0) {
        atomicAdd(&ssum[l], ss0);      atomicAdd(&ssq[l], qq0);
        atomicAdd(&ssum[16 + l], ss1); atomicAdd(&ssq[16 + l], qq1);
    }
    __syncthreads();
    if (tid < Fn) {
        atomicAdd(&s2[b * Fn + tid], ssum[tid]);
        atomicAdd(&q2[b * Fn + tid], ssq[tid]);
    }
}

// ---------------- IN2 -> ReLU -> +x -> ReLU, transpose to [b][f][c][t] ----------------
__global__ __launch_bounds__(256) void k_final(const ushort* __restrict__ bufC,
                                               const float* __restrict__ x,
                                               const float* __restrict__ s2,
                                               const float* __restrict__ q2,
                                               float* __restrict__ out) {
    __shared__ float yl[Tn * 33];
    int tid = threadIdx.x;
    int blk = blockIdx.x;
    int b = blk >> 12, c = blk & (Cn - 1);
    {
        uint2 v = ((const uint2*)(bufC + (size_t)(b * Cn + c) * PLANE))[tid];
        int t = tid >> 3, f0 = (tid & 7) * 4;
        yl[t * 33 + f0 + 0] = bflo(v.x);
        yl[t * 33 + f0 + 1] = bfhi(v.x);
        yl[t * 33 + f0 + 2] = bflo(v.y);
        yl[t * 33 + f0 + 3] = bfhi(v.y);
    }
    __syncthreads();
    int f = tid >> 3, tb = (tid & 7) * 4;
    const float invN = 1.0f / (float)(Cn * Tn);
    float mu = s2[b * Fn + f] * invN;
    float var = q2[b * Fn + f] * invN - mu * mu;
    float r = rsqrtf(var + 1e-5f);
    size_t base = ((size_t)(b * Fn + f) * Cn + c) * Tn + tb;
    float4 xv = *(const float4*)(x + base);
    float xx[4] = {xv.x, xv.y, xv.z, xv.w};
    float oo[4];
    #pragma unroll
    for (int j = 0; j < 4; ++j) {
        float y = yl[(tb + j) * 33 + f];
        float yn = fmaxf(0.f, (y - mu) * r);
        oo[j] = fmaxf(0.f, yn + xx[j]);
    }
    *(float4*)(out + base) = make_float4(oo[0], oo[1], oo[2], oo[3]);
}

extern "C" void kernel_launch(void* const* d_in, const int* in_sizes, int n_in,
                              void* d_out, int out_size, void* d_ws, size_t ws_size,
                              hipStream_t stream) {
    const float* x  = (const float*)d_in[0];
    const int*   ei = (const int*)d_in[1];
    const float* ew = (const float*)d_in[2];
    const float* W  = (const float*)d_in[3];
    const float* gb = (const float*)d_in[4];
    const float* cw = (const float*)d_in[5];
    const float* cb = (const float*)d_in[6];
    float* out = (float*)d_out;

    char* p = (char*)d_ws;
    auto alloc = [&](size_t bytes) {
        char* r = p;
        p += (bytes + 255) & ~(size_t)255;
        return r;
    };
    ushort* bufA = (ushort*)alloc(sizeof(ushort) * (size_t)Bn * Cn * PLANE);  // 32 MB
    ushort* bufB = (ushort*)alloc(sizeof(ushort) * (size_t)Bn * Cn * PLANE);  // 32 MB
    ushort* bufC = (ushort*)alloc(sizeof(ushort) * (size_t)Bn * Cn * PLANE);  // 32 MB
    float* deg  = (float*)alloc(sizeof(float) * Cn);
    int*   hist = (int*)alloc(sizeof(int) * Cn);
    int*   cnt  = (int*)alloc(sizeof(int) * Cn);
    int*   ptr  = (int*)alloc(sizeof(int) * (Cn + 1));
    int*   csrs = (int*)alloc(sizeof(int) * En);
    float* csrw = (float*)alloc(sizeof(float) * En);
    float* s1   = (float*)alloc(sizeof(float) * Bn * Fn);
    float* q1   = (float*)alloc(sizeof(float) * Bn * Fn);
    float* s2   = (float*)alloc(sizeof(float) * Bn * Fn);
    float* q2   = (float*)alloc(sizeof(float) * Bn * Fn);
    ushort* wfrag = (ushort*)alloc(sizeof(ushort) * 2 * 9 * 64 * 8);  // 18 KB
    if ((size_t)(p - (char*)d_ws) > ws_size) return;  // insufficient workspace

    k_init<<<Cn / 256, 256, 0, stream>>>(deg, hist, cnt, s1, q1, s2, q2, cw, wfrag);
    k_deg<<<En / 256, 256, 0, stream>>>(ei, ew, deg, hist);
    k_scan<<<1, 1024, 0, stream>>>(hist, ptr);
    k_fill<<<En / 256, 256, 0, stream>>>(ei, ew, deg, ptr, cnt, csrs, csrw);
    k_xlin<<<Bn * (Cn / 8), 256, 0, stream>>>(x, W, bufA);
    k_agg<<<Cn * 2, 256, 0, stream>>>(bufA, deg, ptr, csrs, csrw, gb, bufB, s1, q1);
    k_convm<<<Bn * (Cn / 8), 256, 0, stream>>>(bufB, s1, q1, wfrag, cb, bufC, s2, q2);
    k_final<<<Bn * Cn, 256, 0, stream>>>(bufC, x, s2, q2, out);
}

// Round 11
// 176.684 us; speedup vs baseline: 1.1091x; 1.1091x over previous
//
#include <hip/hip_runtime.h>
#include <cstddef>

namespace {
constexpr int Bn = 4, Fn = 32, Cn = 4096, Tn = 32, En = 65536, Kw = 9;
constexpr int PLANE = Tn * Fn;   // 1024 elems per (b,c) plane
}

typedef __attribute__((ext_vector_type(8))) short bf16x8;
typedef __attribute__((ext_vector_type(4))) float f32x4;

static __device__ __forceinline__ unsigned short f2bf(float f) {
    unsigned int u = __float_as_uint(f);
    unsigned int r = (u + 0x7fffu + ((u >> 16) & 1u)) >> 16;
    return (unsigned short)r;
}
// unpack uint (2 bf16) -> 2 floats: lo = u<<16, hi = u & 0xffff0000
static __device__ __forceinline__ float bflo(unsigned u) { return __uint_as_float(u << 16); }
static __device__ __forceinline__ float bfhi(unsigned u) { return __uint_as_float(u & 0xffff0000u); }

// ---------------- init (deg=1, hist=cnt=0, stats=0) + conv-weight fragments ----------------
__global__ __launch_bounds__(256) void k_init(float* deg, int* hist, int* cnt,
                                              float* s1, float* q1, float* s2, float* q2,
                                              const float* __restrict__ cw,
                                              ushort* __restrict__ wfrag) {
    int i = blockIdx.x * 256 + threadIdx.x;
    if (i < Cn) { deg[i] = 1.0f; hist[i] = 0; cnt[i] = 0; }
    if (i < Bn * Fn) { s1[i] = 0.f; q1[i] = 0.f; s2[i] = 0.f; q2[i] = 0.f; }
    if (i < 2 * 9 * 64) {
        int l  = i & 63;
        int k  = (i >> 6) % 9;
        int nt = i / 576;
        int o  = nt * 16 + (l & 15);
        int ib = (l >> 4) * 8;
        ushort v[8];
        #pragma unroll
        for (int j = 0; j < 8; ++j) v[j] = f2bf(cw[o * 288 + (ib + j) * 9 + k]);
        uint4 pk;
        pk.x = (unsigned)v[0] | ((unsigned)v[1] << 16);
        pk.y = (unsigned)v[2] | ((unsigned)v[3] << 16);
        pk.z = (unsigned)v[4] | ((unsigned)v[5] << 16);
        pk.w = (unsigned)v[6] | ((unsigned)v[7] << 16);
        ((uint4*)wfrag)[i] = pk;
    }
}

// ---------------- degree + dst histogram ----------------
__global__ __launch_bounds__(256) void k_deg(const int* ei, const float* ew, float* deg, int* hist) {
    int e = blockIdx.x * 256 + threadIdx.x;
    int d = ei[En + e];
    atomicAdd(&deg[d], ew[e]);
    atomicAdd(&hist[d], 1);
}

// ---------------- exclusive scan of hist (C=4096, one block) ----------------
__global__ __launch_bounds__(1024) void k_scan(const int* hist, int* ptr) {
    __shared__ int part[1024];
    int tid = threadIdx.x;
    int v0 = hist[tid*4+0], v1 = hist[tid*4+1], v2 = hist[tid*4+2], v3 = hist[tid*4+3];
    int tot = v0 + v1 + v2 + v3;
    part[tid] = tot;
    __syncthreads();
    for (int off = 1; off < 1024; off <<= 1) {
        int add = (tid >= off) ? part[tid - off] : 0;
        __syncthreads();
        part[tid] += add;
        __syncthreads();
    }
    int run = part[tid] - tot;  // exclusive base
    ptr[tid*4+0] = run; run += v0;
    ptr[tid*4+1] = run; run += v1;
    ptr[tid*4+2] = run; run += v2;
    ptr[tid*4+3] = run; run += v3;
    if (tid == 1023) ptr[4096] = run;
}

// ---------------- CSR fill (sorted by dst) with fused norm ----------------
__global__ __launch_bounds__(256) void k_fill(const int* ei, const float* ew, const float* deg,
                                              const int* ptr, int* cnt, int* csrs, float* csrw) {
    int e = blockIdx.x * 256 + threadIdx.x;
    int s = ei[e];
    int d = ei[En + e];
    float w = rsqrtf(deg[s]) * ew[e] * rsqrtf(deg[d]);
    int pos = ptr[d] + atomicAdd(&cnt[d], 1);
    csrs[pos] = s;
    csrw[pos] = w;
}

// ---------------- x_lin[b][c][t][g] (bf16) = sum_f x[b,f,c,t] * W[f,g] ----------------
__global__ __launch_bounds__(256) void k_xlin(const float* __restrict__ x,
                                              const float* __restrict__ W,
                                              ushort* __restrict__ bufA) {
    __shared__ float wl[Fn * Fn];
    int tid = threadIdx.x;
    ((float4*)wl)[tid] = ((const float4*)W)[tid];
    int b  = blockIdx.x >> 9;           // / 512
    int c0 = (blockIdx.x & 511) << 3;   // 8 nodes per block
    __syncthreads();

    float acc[Fn];
    #pragma unroll
    for (int g = 0; g < Fn; ++g) acc[g] = 0.f;

    const float* xp = x + (size_t)b * Fn * Cn * Tn + (size_t)c0 * Tn + tid;
    #pragma unroll
    for (int f = 0; f < Fn; ++f) {
        float xv = xp[(size_t)f * Cn * Tn];
        #pragma unroll
        for (int g = 0; g < Fn; ++g) acc[g] += xv * wl[f * Fn + g];
    }
    ushort* op = bufA + (size_t)(b * Cn + c0) * PLANE + tid * Fn;
    #pragma unroll
    for (int g8 = 0; g8 < 4; ++g8) {
        uint4 pk;
        pk.x = (unsigned)f2bf(acc[g8*8+0]) | ((unsigned)f2bf(acc[g8*8+1]) << 16);
        pk.y = (unsigned)f2bf(acc[g8*8+2]) | ((unsigned)f2bf(acc[g8*8+3]) << 16);
        pk.z = (unsigned)f2bf(acc[g8*8+4]) | ((unsigned)f2bf(acc[g8*8+5]) << 16);
        pk.w = (unsigned)f2bf(acc[g8*8+6]) | ((unsigned)f2bf(acc[g8*8+7]) << 16);
        ((uint4*)op)[g8] = pk;
    }
}

// ---------------- GCN aggregation, XCD-L2-tiled SpMM, 8-deep gather pipeline ----------------
// Round-7 structure (best measured) + non-temporal output stores (keeps the
// 4 MB gather pool L2-resident; NT store validated in round 10).
__global__ __launch_bounds__(256) void k_agg(const ushort* __restrict__ bufA,
                                             const float* __restrict__ deg,
                                             const int* __restrict__ ptr,
                                             const int* __restrict__ csrs,
                                             const float* __restrict__ csrw,
                                             const float* __restrict__ gb,
                                             ushort* __restrict__ bufB,
                                             float* s1, float* q1) {
    __shared__ float ssum[Fn], ssq[Fn];
    int tid = threadIdx.x;
    int tile = blockIdx.x & 7;
    int chunk = blockIdx.x >> 3;          // 512 chunks
    int b = tile >> 1, half = tile & 1;
    int c0 = chunk * 8;
    if (tid < Fn) { ssum[tid] = 0.f; ssq[tid] = 0.f; }

    const ushort* base = bufA + (size_t)b * Cn * PLANE + half * 512;
    ushort* obase = bufB + (size_t)b * Cn * PLANE + half * 512;
    int e0 = tid * 2;                      // elem pair within the 512-slice
    int f0 = e0 & 31;                      // even f
    float g0 = gb[f0], g1 = gb[f0 + 1];

    float st0 = 0.f, st1 = 0.f, sq0 = 0.f, sq1 = 0.f;
    for (int cc = 0; cc < 8; ++cc) {
        int c = c0 + cc;
        float d2 = 1.0f / deg[c];
        unsigned sv = *(const unsigned*)(base + (size_t)c * PLANE + e0);
        float ax = bflo(sv) * d2, ay = bfhi(sv) * d2;

        int j0 = ptr[c], j1 = ptr[c + 1];
        int j = j0;
        for (; j + 7 < j1; j += 8) {
            int s[8]; float w[8]; unsigned u[8];
            #pragma unroll
            for (int i = 0; i < 8; ++i) { s[i] = csrs[j + i]; w[i] = csrw[j + i]; }
            #pragma unroll
            for (int i = 0; i < 8; ++i)
                u[i] = *(const unsigned*)(base + (size_t)s[i] * PLANE + e0);
            #pragma unroll
            for (int i = 0; i < 8; ++i) {
                ax += bflo(u[i]) * w[i];
                ay += bfhi(u[i]) * w[i];
            }
        }
        if (j + 3 < j1) {
            int s[4]; float w[4]; unsigned u[4];
            #pragma unroll
            for (int i = 0; i < 4; ++i) { s[i] = csrs[j + i]; w[i] = csrw[j + i]; }
            #pragma unroll
            for (int i = 0; i < 4; ++i)
                u[i] = *(const unsigned*)(base + (size_t)s[i] * PLANE + e0);
            #pragma unroll
            for (int i = 0; i < 4; ++i) {
                ax += bflo(u[i]) * w[i];
                ay += bfhi(u[i]) * w[i];
            }
            j += 4;
        }
        for (; j < j1; ++j) {
            int s0 = csrs[j];
            float w0 = csrw[j];
            unsigned u0 = *(const unsigned*)(base + (size_t)s0 * PLANE + e0);
            ax += bflo(u0) * w0; ay += bfhi(u0) * w0;
        }
        ax += g0; ay += g1;
        unsigned pk = (unsigned)f2bf(ax) | ((unsigned)f2bf(ay) << 16);
        __builtin_nontemporal_store(pk, (unsigned*)(obase + (size_t)c * PLANE + e0));
        st0 += ax; sq0 += ax * ax; st1 += ay; sq1 += ay * ay;
    }

    // lanes l, l+16, l+32, l+48 share f -> shfl reduce, then LDS atomics
    st0 += __shfl_xor(st0, 16); st0 += __shfl_xor(st0, 32);
    sq0 += __shfl_xor(sq0, 16); sq0 += __shfl_xor(sq0, 32);
    st1 += __shfl_xor(st1, 16); st1 += __shfl_xor(st1, 32);
    sq1 += __shfl_xor(sq1, 16); sq1 += __shfl_xor(sq1, 32);
    __syncthreads();  // ssum/ssq zeroed
    if ((tid & 63) < 16) {
        int l = tid & 15;
        atomicAdd(&ssum[2*l],     st0); atomicAdd(&ssq[2*l],     sq0);
        atomicAdd(&ssum[2*l + 1], st1); atomicAdd(&ssq[2*l + 1], sq1);
    }
    __syncthreads();
    if (tid < Fn) {
        atomicAdd(&s1[b * Fn + tid], ssum[tid]);
        atomicAdd(&q1[b * Fn + tid], ssq[tid]);
    }
}

// ---------------- IN1 -> ReLU -> Conv(1xK) via bf16 MFMA + IN2 stats ----------------
__global__ __launch_bounds__(256) void k_convm(const ushort* __restrict__ bufB,
                                               const float* __restrict__ s1,
                                               const float* __restrict__ q1,
                                               const ushort* __restrict__ wfrag,
                                               const float* __restrict__ cb,
                                               ushort* __restrict__ bufC,
                                               float* s2, float* q2) {
    __shared__ __align__(16) ushort zbuf[4 * 40 * 72];
    __shared__ float ssum[Fn], ssq[Fn];
    int tid = threadIdx.x;
    int l = tid & 63, w = tid >> 6;
    int b  = blockIdx.x >> 9;                 // 512 blocks per b
    int c0 = (blockIdx.x & 511) * 8 + w * 2;  // 2 planes per wave

    if (tid < Fn) { ssum[tid] = 0.f; ssq[tid] = 0.f; }

    ushort* z = zbuf + w * (40 * 72);
    if (l < 16) {  // zero pad rows 0..3 and 36..39, cols 0..31 (only ones read)
        #pragma unroll
        for (int p = 0; p < 4; ++p) {
            *(unsigned*)&z[p * 72 + l * 2] = 0u;
            *(unsigned*)&z[(36 + p) * 72 + l * 2] = 0u;
        }
    }

    // B fragments resident in VGPRs
    bf16x8 wf0[9], wf1[9];
    #pragma unroll
    for (int k = 0; k < Kw; ++k) {
        wf0[k] = *(const bf16x8*)(wfrag + ((0 * 9 + k) * 64 + l) * 8);
        wf1[k] = *(const bf16x8*)(wfrag + ((1 * 9 + k) * 64 + l) * 8);
    }
    // IN1 finalize inline: f = (l&1)*16 + j ; pm = -mu*r, pr = r
    const float invN = 1.0f / (float)(Cn * Tn);
    float pm[16], pr[16];
    {
        int fb = b * Fn + (l & 1) * 16;
        #pragma unroll
        for (int j = 0; j < 16; ++j) {
            float mu = s1[fb + j] * invN;
            float var = q1[fb + j] * invN - mu * mu;
            float r = rsqrtf(var + 1e-5f);
            pm[j] = -mu * r; pr[j] = r;
        }
    }
    float cbv0 = cb[l & 15], cbv1 = cb[16 + (l & 15)];
    __syncthreads();

    float ss0 = 0.f, ss1 = 0.f, qq0 = 0.f, qq1 = 0.f;
    const ushort* za = z + (l & 15) * 72 + (l >> 4) * 8;

    for (int p = 0; p < 2; ++p) {
        int c = c0 + p;
        // ---- build z: load bf16 plane, IN1-normalize + ReLU, back to bf16 ----
        const ushort* src = bufB + (size_t)(b * Cn + c) * PLANE + l * 16;
        uint4 i0 = *(const uint4*)(src);
        uint4 i1 = *(const uint4*)(src + 8);
        float iv[16] = { bflo(i0.x), bfhi(i0.x), bflo(i0.y), bfhi(i0.y),
                         bflo(i0.z), bfhi(i0.z), bflo(i0.w), bfhi(i0.w),
                         bflo(i1.x), bfhi(i1.x), bflo(i1.y), bfhi(i1.y),
                         bflo(i1.z), bfhi(i1.z), bflo(i1.w), bfhi(i1.w) };
        ushort tmp[16];
        #pragma unroll
        for (int j = 0; j < 16; ++j)
            tmp[j] = f2bf(fmaxf(0.f, iv[j] * pr[j] + pm[j]));
        {
            int t = l >> 1, h = l & 1;
            ushort* zw = z + (t + 4) * 72 + h * 16;
            uint4 w0, w1;
            w0.x = (unsigned)tmp[0] | ((unsigned)tmp[1] << 16);
            w0.y = (unsigned)tmp[2] | ((unsigned)tmp[3] << 16);
            w0.z = (unsigned)tmp[4] | ((unsigned)tmp[5] << 16);
            w0.w = (unsigned)tmp[6] | ((unsigned)tmp[7] << 16);
            w1.x = (unsigned)tmp[8] | ((unsigned)tmp[9] << 16);
            w1.y = (unsigned)tmp[10] | ((unsigned)tmp[11] << 16);
            w1.z = (unsigned)tmp[12] | ((unsigned)tmp[13] << 16);
            w1.w = (unsigned)tmp[14] | ((unsigned)tmp[15] << 16);
            *(uint4*)(zw) = w0;
            *(uint4*)(zw + 8) = w1;
        }
        // same-wave LDS write->read dependency: compiler inserts lgkmcnt waits

        // ---- MFMA: D[32t x 32o] = A[32t x 288] * B[288 x 32o] ----
        f32x4 acc00 = {0,0,0,0}, acc01 = {0,0,0,0}, acc10 = {0,0,0,0}, acc11 = {0,0,0,0};
        #pragma unroll
        for (int k = 0; k < Kw; ++k) {
            bf16x8 a0 = *(const bf16x8*)(za + k * 72);
            acc00 = __builtin_amdgcn_mfma_f32_16x16x32_bf16(a0, wf0[k], acc00, 0, 0, 0);
            acc01 = __builtin_amdgcn_mfma_f32_16x16x32_bf16(a0, wf1[k], acc01, 0, 0, 0);
        }
        #pragma unroll
        for (int k = 0; k < Kw; ++k) {
            bf16x8 a1 = *(const bf16x8*)(za + (16 + k) * 72);
            acc10 = __builtin_amdgcn_mfma_f32_16x16x32_bf16(a1, wf0[k], acc10, 0, 0, 0);
            acc11 = __builtin_amdgcn_mfma_f32_16x16x32_bf16(a1, wf1[k], acc11, 0, 0, 0);
        }

        // ---- epilogue: +bias, store bf16, IN2 partial stats (fp32) ----
        ushort* dst = bufC + (size_t)(b * Cn + c) * PLANE;
        int col = l & 15, r0 = (l >> 4) * 4;
        #pragma unroll
        for (int r = 0; r < 4; ++r) {
            float v00 = acc00[r] + cbv0;
            float v01 = acc01[r] + cbv1;
            float v10 = acc10[r] + cbv0;
            float v11 = acc11[r] + cbv1;
            dst[(r0 + r) * 32 + col]            = f2bf(v00);
            dst[(r0 + r) * 32 + 16 + col]       = f2bf(v01);
            dst[(16 + r0 + r) * 32 + col]       = f2bf(v10);
            dst[(16 + r0 + r) * 32 + 16 + col]  = f2bf(v11);
            ss0 += v00 + v10; qq0 += v00 * v00 + v10 * v10;
            ss1 += v01 + v11; qq1 += v01 * v01 + v11 * v11;
        }
    }

    // ---- reduce stats across the 4 lane-groups, accumulate to block LDS ----
    ss0 += __shfl_xor(ss0, 16); ss0 += __shfl_xor(ss0, 32);
    qq0 += __shfl_xor(qq0, 16); qq0 += __shfl_xor(qq0, 32);
    ss1 += __shfl_xor(ss1, 16); ss1 += __shfl_xor(ss1, 32);
    qq1 += __shfl_xor(qq1, 16); qq1 += __shfl_xor(qq1, 32);
    if ((l >> 4) == 0) {
        atomicAdd(&ssum[l], ss0);      atomicAdd(&ssq[l], qq0);
        atomicAdd(&ssum[16 + l], ss1); atomicAdd(&ssq[16 + l], qq1);
    }
    __syncthreads();
    if (tid < Fn) {
        atomicAdd(&s2[b * Fn + tid], ssum[tid]);
        atomicAdd(&q2[b * Fn + tid], ssq[tid]);
    }
}

// ---------------- IN2 -> ReLU -> +x -> ReLU, transpose to [b][f][c][t] ----------------
__global__ __launch_bounds__(256) void k_final(const ushort* __restrict__ bufC,
                                               const float* __restrict__ x,
                                               const float* __restrict__ s2,
                                               const float* __restrict__ q2,
                                               float* __restrict__ out) {
    __shared__ float yl[Tn * 33];
    int tid = threadIdx.x;
    int blk = blockIdx.x;
    int b = blk >> 12, c = blk & (Cn - 1);
    {
        uint2 v = ((const uint2*)(bufC + (size_t)(b * Cn + c) * PLANE))[tid];
        int t = tid >> 3, f0 = (tid & 7) * 4;
        yl[t * 33 + f0 + 0] = bflo(v.x);
        yl[t * 33 + f0 + 1] = bfhi(v.x);
        yl[t * 33 + f0 + 2] = bflo(v.y);
        yl[t * 33 + f0 + 3] = bfhi(v.y);
    }
    __syncthreads();
    int f = tid >> 3, tb = (tid & 7) * 4;
    const float invN = 1.0f / (float)(Cn * Tn);
    float mu = s2[b * Fn + f] * invN;
    float var = q2[b * Fn + f] * invN - mu * mu;
    float r = rsqrtf(var + 1e-5f);
    size_t base = ((size_t)(b * Fn + f) * Cn + c) * Tn + tb;
    float4 xv = *(const float4*)(x + base);
    float xx[4] = {xv.x, xv.y, xv.z, xv.w};
    float oo[4];
    #pragma unroll
    for (int j = 0; j < 4; ++j) {
        float y = yl[(tb + j) * 33 + f];
        float yn = fmaxf(0.f, (y - mu) * r);
        oo[j] = fmaxf(0.f, yn + xx[j]);
    }
    *(float4*)(out + base) = make_float4(oo[0], oo[1], oo[2], oo[3]);
}

extern "C" void kernel_launch(void* const* d_in, const int* in_sizes, int n_in,
                              void* d_out, int out_size, void* d_ws, size_t ws_size,
                              hipStream_t stream) {
    const float* x  = (const float*)d_in[0];
    const int*   ei = (const int*)d_in[1];
    const float* ew = (const float*)d_in[2];
    const float* W  = (const float*)d_in[3];
    const float* gb = (const float*)d_in[4];
    const float* cw = (const float*)d_in[5];
    const float* cb = (const float*)d_in[6];
    float* out = (float*)d_out;

    char* p = (char*)d_ws;
    auto alloc = [&](size_t bytes) {
        char* r = p;
        p += (bytes + 255) & ~(size_t)255;
        return r;
    };
    ushort* bufA = (ushort*)alloc(sizeof(ushort) * (size_t)Bn * Cn * PLANE);  // 32 MB
    ushort* bufB = (ushort*)alloc(sizeof(ushort) * (size_t)Bn * Cn * PLANE);  // 32 MB
    ushort* bufC = (ushort*)alloc(sizeof(ushort) * (size_t)Bn * Cn * PLANE);  // 32 MB
    float* deg  = (float*)alloc(sizeof(float) * Cn);
    int*   hist = (int*)alloc(sizeof(int) * Cn);
    int*   cnt  = (int*)alloc(sizeof(int) * Cn);
    int*   ptr  = (int*)alloc(sizeof(int) * (Cn + 1));
    int*   csrs = (int*)alloc(sizeof(int) * En);
    float* csrw = (float*)alloc(sizeof(float) * En);
    float* s1   = (float*)alloc(sizeof(float) * Bn * Fn);
    float* q1   = (float*)alloc(sizeof(float) * Bn * Fn);
    float* s2   = (float*)alloc(sizeof(float) * Bn * Fn);
    float* q2   = (float*)alloc(sizeof(float) * Bn * Fn);
    ushort* wfrag = (ushort*)alloc(sizeof(ushort) * 2 * 9 * 64 * 8);  // 18 KB
    if ((size_t)(p - (char*)d_ws) > ws_size) return;  // insufficient workspace

    k_init<<<Cn / 256, 256, 0, stream>>>(deg, hist, cnt, s1, q1, s2, q2, cw, wfrag);
    k_deg<<<En / 256, 256, 0, stream>>>(ei, ew, deg, hist);
    k_scan<<<1, 1024, 0, stream>>>(hist, ptr);
    k_fill<<<En / 256, 256, 0, stream>>>(ei, ew, deg, ptr, cnt, csrs, csrw);
    k_xlin<<<Bn * (Cn / 8), 256, 0, stream>>>(x, W, bufA);
    k_agg<<<Cn, 256, 0, stream>>>(bufA, deg, ptr, csrs, csrw, gb, bufB, s1, q1);
    k_convm<<<Bn * (Cn / 8), 256, 0, stream>>>(bufB, s1, q1, wfrag, cb, bufC, s2, q2);
    k_final<<<Bn * Cn, 256, 0, stream>>>(bufC, x, s2, q2, out);
}

// Round 12
// 160.695 us; speedup vs baseline: 1.2195x; 1.0995x over previous
//
#include <hip/hip_runtime.h>
#include <cstddef>

namespace {
constexpr int Bn = 4, Fn = 32, Cn = 4096, Tn = 32, En = 65536, Kw = 9;
constexpr int PLANE = Tn * Fn;   // 1024 elems per (b,c) plane
}

typedef __attribute__((ext_vector_type(8))) short bf16x8;
typedef __attribute__((ext_vector_type(4))) float f32x4;

static __device__ __forceinline__ unsigned short f2bf(float f) {
    unsigned int u = __float_as_uint(f);
    unsigned int r = (u + 0x7fffu + ((u >> 16) & 1u)) >> 16;
    return (unsigned short)r;
}
// unpack uint (2 bf16) -> 2 floats: lo = u<<16, hi = u & 0xffff0000
static __device__ __forceinline__ float bflo(unsigned u) { return __uint_as_float(u << 16); }
static __device__ __forceinline__ float bfhi(unsigned u) { return __uint_as_float(u & 0xffff0000u); }

// ---------------- init (deg=1, hist=cnt=0, stats=0) + conv-weight fragments ----------------
__global__ __launch_bounds__(256) void k_init(float* deg, int* hist, int* cnt,
                                              float* s1, float* q1, float* s2, float* q2,
                                              const float* __restrict__ cw,
                                              ushort* __restrict__ wfrag) {
    int i = blockIdx.x * 256 + threadIdx.x;
    if (i < Cn) { deg[i] = 1.0f; hist[i] = 0; cnt[i] = 0; }
    if (i < Bn * Fn) { s1[i] = 0.f; q1[i] = 0.f; s2[i] = 0.f; q2[i] = 0.f; }
    if (i < 2 * 9 * 64) {
        int l  = i & 63;
        int k  = (i >> 6) % 9;
        int nt = i / 576;
        int o  = nt * 16 + (l & 15);
        int ib = (l >> 4) * 8;
        ushort v[8];
        #pragma unroll
        for (int j = 0; j < 8; ++j) v[j] = f2bf(cw[o * 288 + (ib + j) * 9 + k]);
        uint4 pk;
        pk.x = (unsigned)v[0] | ((unsigned)v[1] << 16);
        pk.y = (unsigned)v[2] | ((unsigned)v[3] << 16);
        pk.z = (unsigned)v[4] | ((unsigned)v[5] << 16);
        pk.w = (unsigned)v[6] | ((unsigned)v[7] << 16);
        ((uint4*)wfrag)[i] = pk;
    }
}

// ---------------- degree + dst histogram ----------------
__global__ __launch_bounds__(256) void k_deg(const int* ei, const float* ew, float* deg, int* hist) {
    int e = blockIdx.x * 256 + threadIdx.x;
    int d = ei[En + e];
    atomicAdd(&deg[d], ew[e]);
    atomicAdd(&hist[d], 1);
}

// ---------------- exclusive scan of hist (C=4096, one block) ----------------
__global__ __launch_bounds__(1024) void k_scan(const int* hist, int* ptr) {
    __shared__ int part[1024];
    int tid = threadIdx.x;
    int v0 = hist[tid*4+0], v1 = hist[tid*4+1], v2 = hist[tid*4+2], v3 = hist[tid*4+3];
    int tot = v0 + v1 + v2 + v3;
    part[tid] = tot;
    __syncthreads();
    for (int off = 1; off < 1024; off <<= 1) {
        int add = (tid >= off) ? part[tid - off] : 0;
        __syncthreads();
        part[tid] += add;
        __syncthreads();
    }
    int run = part[tid] - tot;  // exclusive base
    ptr[tid*4+0] = run; run += v0;
    ptr[tid*4+1] = run; run += v1;
    ptr[tid*4+2] = run; run += v2;
    ptr[tid*4+3] = run; run += v3;
    if (tid == 1023) ptr[4096] = run;
}

// ---------------- CSR fill (sorted by dst) with fused norm ----------------
__global__ __launch_bounds__(256) void k_fill(const int* ei, const float* ew, const float* deg,
                                              const int* ptr, int* cnt, int* csrs, float* csrw) {
    int e = blockIdx.x * 256 + threadIdx.x;
    int s = ei[e];
    int d = ei[En + e];
    float w = rsqrtf(deg[s]) * ew[e] * rsqrtf(deg[d]);
    int pos = ptr[d] + atomicAdd(&cnt[d], 1);
    csrs[pos] = s;
    csrw[pos] = w;
}

// ---------------- x_lin via MFMA: bufA[b][c][t][g] (bf16) = sum_f x[b,f,c,t]*W[f,g] ----------------
// One wave per (b,c) plane. A[t][f] = x slices (coalesced 64B segs), B[f][g] = W (bf16).
__global__ __launch_bounds__(256) void k_xlin(const float* __restrict__ x,
                                              const float* __restrict__ W,
                                              ushort* __restrict__ bufA) {
    int tid = threadIdx.x;
    int l = tid & 63, w = tid >> 6;
    int b = blockIdx.x >> 10;                  // 1024 blocks per b
    int c = (blockIdx.x & 1023) * 4 + w;       // one plane per wave
    int row = l & 15, kg = l >> 4;             // A row (t), k-group (f block)

    // B fragments: B[f=kg*8+j][g=row (+16)]
    bf16x8 wf0, wf1;
    #pragma unroll
    for (int j = 0; j < 8; ++j) {
        wf0[j] = (short)f2bf(W[(kg * 8 + j) * Fn + row]);
        wf1[j] = (short)f2bf(W[(kg * 8 + j) * Fn + 16 + row]);
    }

    // A fragments: A[t=row(+16)][f=kg*8+j] = x[b][f][c][t]
    const float* xp = x + ((size_t)(b * Fn) * Cn + c) * Tn;
    bf16x8 a0, a1;
    #pragma unroll
    for (int j = 0; j < 8; ++j) {
        size_t fo = (size_t)(kg * 8 + j) * Cn * Tn;
        a0[j] = (short)f2bf(xp[fo + row]);
        a1[j] = (short)f2bf(xp[fo + 16 + row]);
    }

    f32x4 d00 = {0,0,0,0}, d01 = {0,0,0,0}, d10 = {0,0,0,0}, d11 = {0,0,0,0};
    d00 = __builtin_amdgcn_mfma_f32_16x16x32_bf16(a0, wf0, d00, 0, 0, 0);
    d01 = __builtin_amdgcn_mfma_f32_16x16x32_bf16(a0, wf1, d01, 0, 0, 0);
    d10 = __builtin_amdgcn_mfma_f32_16x16x32_bf16(a1, wf0, d10, 0, 0, 0);
    d11 = __builtin_amdgcn_mfma_f32_16x16x32_bf16(a1, wf1, d11, 0, 0, 0);

    // D layout: col = l&15 (g), row = (l>>4)*4 + r (t)
    ushort* op = bufA + (size_t)(b * Cn + c) * PLANE;
    int col = l & 15, r0 = (l >> 4) * 4;
    #pragma unroll
    for (int r = 0; r < 4; ++r) {
        op[(r0 + r) * Fn + col]           = f2bf(d00[r]);
        op[(r0 + r) * Fn + 16 + col]      = f2bf(d01[r]);
        op[(16 + r0 + r) * Fn + col]      = f2bf(d10[r]);
        op[(16 + r0 + r) * Fn + 16 + col] = f2bf(d11[r]);
    }
}

// ---------------- GCN aggregation, XCD-L2-tiled SpMM, 8-deep gather pipeline ----------------
// Round-7 structure (best measured) + non-temporal output stores (keeps the
// 4 MB gather pool L2-resident).
__global__ __launch_bounds__(256) void k_agg(const ushort* __restrict__ bufA,
                                             const float* __restrict__ deg,
                                             const int* __restrict__ ptr,
                                             const int* __restrict__ csrs,
                                             const float* __restrict__ csrw,
                                             const float* __restrict__ gb,
                                             ushort* __restrict__ bufB,
                                             float* s1, float* q1) {
    __shared__ float ssum[Fn], ssq[Fn];
    int tid = threadIdx.x;
    int tile = blockIdx.x & 7;
    int chunk = blockIdx.x >> 3;          // 512 chunks
    int b = tile >> 1, half = tile & 1;
    int c0 = chunk * 8;
    if (tid < Fn) { ssum[tid] = 0.f; ssq[tid] = 0.f; }

    const ushort* base = bufA + (size_t)b * Cn * PLANE + half * 512;
    ushort* obase = bufB + (size_t)b * Cn * PLANE + half * 512;
    int e0 = tid * 2;                      // elem pair within the 512-slice
    int f0 = e0 & 31;                      // even f
    float g0 = gb[f0], g1 = gb[f0 + 1];

    float st0 = 0.f, st1 = 0.f, sq0 = 0.f, sq1 = 0.f;
    for (int cc = 0; cc < 8; ++cc) {
        int c = c0 + cc;
        float d2 = 1.0f / deg[c];
        unsigned sv = *(const unsigned*)(base + (size_t)c * PLANE + e0);
        float ax = bflo(sv) * d2, ay = bfhi(sv) * d2;

        int j0 = ptr[c], j1 = ptr[c + 1];
        int j = j0;
        for (; j + 7 < j1; j += 8) {
            int s[8]; float w[8]; unsigned u[8];
            #pragma unroll
            for (int i = 0; i < 8; ++i) { s[i] = csrs[j + i]; w[i] = csrw[j + i]; }
            #pragma unroll
            for (int i = 0; i < 8; ++i)
                u[i] = *(const unsigned*)(base + (size_t)s[i] * PLANE + e0);
            #pragma unroll
            for (int i = 0; i < 8; ++i) {
                ax += bflo(u[i]) * w[i];
                ay += bfhi(u[i]) * w[i];
            }
        }
        if (j + 3 < j1) {
            int s[4]; float w[4]; unsigned u[4];
            #pragma unroll
            for (int i = 0; i < 4; ++i) { s[i] = csrs[j + i]; w[i] = csrw[j + i]; }
            #pragma unroll
            for (int i = 0; i < 4; ++i)
                u[i] = *(const unsigned*)(base + (size_t)s[i] * PLANE + e0);
            #pragma unroll
            for (int i = 0; i < 4; ++i) {
                ax += bflo(u[i]) * w[i];
                ay += bfhi(u[i]) * w[i];
            }
            j += 4;
        }
        for (; j < j1; ++j) {
            int s0 = csrs[j];
            float w0 = csrw[j];
            unsigned u0 = *(const unsigned*)(base + (size_t)s0 * PLANE + e0);
            ax += bflo(u0) * w0; ay += bfhi(u0) * w0;
        }
        ax += g0; ay += g1;
        unsigned pk = (unsigned)f2bf(ax) | ((unsigned)f2bf(ay) << 16);
        __builtin_nontemporal_store(pk, (unsigned*)(obase + (size_t)c * PLANE + e0));
        st0 += ax; sq0 += ax * ax; st1 += ay; sq1 += ay * ay;
    }

    // lanes l, l+16, l+32, l+48 share f -> shfl reduce, then LDS atomics
    st0 += __shfl_xor(st0, 16); st0 += __shfl_xor(st0, 32);
    sq0 += __shfl_xor(sq0, 16); sq0 += __shfl_xor(sq0, 32);
    st1 += __shfl_xor(st1, 16); st1 += __shfl_xor(st1, 32);
    sq1 += __shfl_xor(sq1, 16); sq1 += __shfl_xor(sq1, 32);
    __syncthreads();  // ssum/ssq zeroed
    if ((tid & 63) < 16) {
        int l = tid & 15;
        atomicAdd(&ssum[2*l],     st0); atomicAdd(&ssq[2*l],     sq0);
        atomicAdd(&ssum[2*l + 1], st1); atomicAdd(&ssq[2*l + 1], sq1);
    }
    __syncthreads();
    if (tid < Fn) {
        atomicAdd(&s1[b * Fn + tid], ssum[tid]);
        atomicAdd(&q1[b * Fn + tid], ssq[tid]);
    }
}

// ---------------- IN1 -> ReLU -> Conv(1xK) via bf16 MFMA + IN2 stats ----------------
__global__ __launch_bounds__(256) void k_convm(const ushort* __restrict__ bufB,
                                               const float* __restrict__ s1,
                                               const float* __restrict__ q1,
                                               const ushort* __restrict__ wfrag,
                                               const float* __restrict__ cb,
                                               ushort* __restrict__ bufC,
                                               float* s2, float* q2) {
    __shared__ __align__(16) ushort zbuf[4 * 40 * 72];
    __shared__ float ssum[Fn], ssq[Fn];
    int tid = threadIdx.x;
    int l = tid & 63, w = tid >> 6;
    int b  = blockIdx.x >> 9;                 // 512 blocks per b
    int c0 = (blockIdx.x & 511) * 8 + w * 2;  // 2 planes per wave

    if (tid < Fn) { ssum[tid] = 0.f; ssq[tid] = 0.f; }

    ushort* z = zbuf + w * (40 * 72);
    if (l < 16) {  // zero pad rows 0..3 and 36..39, cols 0..31 (only ones read)
        #pragma unroll
        for (int p = 0; p < 4; ++p) {
            *(unsigned*)&z[p * 72 + l * 2] = 0u;
            *(unsigned*)&z[(36 + p) * 72 + l * 2] = 0u;
        }
    }

    // B fragments resident in VGPRs
    bf16x8 wf0[9], wf1[9];
    #pragma unroll
    for (int k = 0; k < Kw; ++k) {
        wf0[k] = *(const bf16x8*)(wfrag + ((0 * 9 + k) * 64 + l) * 8);
        wf1[k] = *(const bf16x8*)(wfrag + ((1 * 9 + k) * 64 + l) * 8);
    }
    // IN1 finalize inline: f = (l&1)*16 + j ; pm = -mu*r, pr = r
    const float invN = 1.0f / (float)(Cn * Tn);
    float pm[16], pr[16];
    {
        int fb = b * Fn + (l & 1) * 16;
        #pragma unroll
        for (int j = 0; j < 16; ++j) {
            float mu = s1[fb + j] * invN;
            float var = q1[fb + j] * invN - mu * mu;
            float r = rsqrtf(var + 1e-5f);
            pm[j] = -mu * r; pr[j] = r;
        }
    }
    float cbv0 = cb[l & 15], cbv1 = cb[16 + (l & 15)];
    __syncthreads();

    float ss0 = 0.f, ss1 = 0.f, qq0 = 0.f, qq1 = 0.f;
    const ushort* za = z + (l & 15) * 72 + (l >> 4) * 8;

    for (int p = 0; p < 2; ++p) {
        int c = c0 + p;
        // ---- build z: load bf16 plane, IN1-normalize + ReLU, back to bf16 ----
        const ushort* src = bufB + (size_t)(b * Cn + c) * PLANE + l * 16;
        uint4 i0 = *(const uint4*)(src);
        uint4 i1 = *(const uint4*)(src + 8);
        float iv[16] = { bflo(i0.x), bfhi(i0.x), bflo(i0.y), bfhi(i0.y),
                         bflo(i0.z), bfhi(i0.z), bflo(i0.w), bfhi(i0.w),
                         bflo(i1.x), bfhi(i1.x), bflo(i1.y), bfhi(i1.y),
                         bflo(i1.z), bfhi(i1.z), bflo(i1.w), bfhi(i1.w) };
        ushort tmp[16];
        #pragma unroll
        for (int j = 0; j < 16; ++j)
            tmp[j] = f2bf(fmaxf(0.f, iv[j] * pr[j] + pm[j]));
        {
            int t = l >> 1, h = l & 1;
            ushort* zw = z + (t + 4) * 72 + h * 16;
            uint4 w0, w1;
            w0.x = (unsigned)tmp[0] | ((unsigned)tmp[1] << 16);
            w0.y = (unsigned)tmp[2] | ((unsigned)tmp[3] << 16);
            w0.z = (unsigned)tmp[4] | ((unsigned)tmp[5] << 16);
            w0.w = (unsigned)tmp[6] | ((unsigned)tmp[7] << 16);
            w1.x = (unsigned)tmp[8] | ((unsigned)tmp[9] << 16);
            w1.y = (unsigned)tmp[10] | ((unsigned)tmp[11] << 16);
            w1.z = (unsigned)tmp[12] | ((unsigned)tmp[13] << 16);
            w1.w = (unsigned)tmp[14] | ((unsigned)tmp[15] << 16);
            *(uint4*)(zw) = w0;
            *(uint4*)(zw + 8) = w1;
        }
        // same-wave LDS write->read dependency: compiler inserts lgkmcnt waits

        // ---- MFMA: D[32t x 32o] = A[32t x 288] * B[288 x 32o] ----
        f32x4 acc00 = {0,0,0,0}, acc01 = {0,0,0,0}, acc10 = {0,0,0,0}, acc11 = {0,0,0,0};
        #pragma unroll
        for (int k = 0; k < Kw; ++k) {
            bf16x8 a0 = *(const bf16x8*)(za + k * 72);
            acc00 = __builtin_amdgcn_mfma_f32_16x16x32_bf16(a0, wf0[k], acc00, 0, 0, 0);
            acc01 = __builtin_amdgcn_mfma_f32_16x16x32_bf16(a0, wf1[k], acc01, 0, 0, 0);
        }
        #pragma unroll
        for (int k = 0; k < Kw; ++k) {
            bf16x8 a1 = *(const bf16x8*)(za + (16 + k) * 72);
            acc10 = __builtin_amdgcn_mfma_f32_16x16x32_bf16(a1, wf0[k], acc10, 0, 0, 0);
            acc11 = __builtin_amdgcn_mfma_f32_16x16x32_bf16(a1, wf1[k], acc11, 0, 0, 0);
        }

        // ---- epilogue: +bias, store bf16, IN2 partial stats (fp32) ----
        ushort* dst = bufC + (size_t)(b * Cn + c) * PLANE;
        int col = l & 15, r0 = (l >> 4) * 4;
        #pragma unroll
        for (int r = 0; r < 4; ++r) {
            float v00 = acc00[r] + cbv0;
            float v01 = acc01[r] + cbv1;
            float v10 = acc10[r] + cbv0;
            float v11 = acc11[r] + cbv1;
            dst[(r0 + r) * 32 + col]            = f2bf(v00);
            dst[(r0 + r) * 32 + 16 + col]       = f2bf(v01);
            dst[(16 + r0 + r) * 32 + col]       = f2bf(v10);
            dst[(16 + r0 + r) * 32 + 16 + col]  = f2bf(v11);
            ss0 += v00 + v10; qq0 += v00 * v00 + v10 * v10;
            ss1 += v01 + v11; qq1 += v01 * v01 + v11 * v11;
        }
    }

    // ---- reduce stats across the 4 lane-groups, accumulate to block LDS ----
    ss0 += __shfl_xor(ss0, 16); ss0 += __shfl_xor(ss0, 32);
    qq0 += __shfl_xor(qq0, 16); qq0 += __shfl_xor(qq0, 32);
    ss1 += __shfl_xor(ss1, 16); ss1 += __shfl_xor(ss1, 32);
    qq1 += __shfl_xor(qq1, 16); qq1 += __shfl_xor(qq1, 32);
    if ((l >> 4) == 0) {
        atomicAdd(&ssum[l], ss0);      atomicAdd(&ssq[l], qq0);
        atomicAdd(&ssum[16 + l], ss1); atomicAdd(&ssq[16 + l], qq1);
    }
    __syncthreads();
    if (tid < Fn) {
        atomicAdd(&s2[b * Fn + tid], ssum[tid]);
        atomicAdd(&q2[b * Fn + tid], ssq[tid]);
    }
}

// ---------------- IN2 -> ReLU -> +x -> ReLU, transpose to [b][f][c][t] ----------------
__global__ __launch_bounds__(256) void k_final(const ushort* __restrict__ bufC,
                                               const float* __restrict__ x,
                                               const float* __restrict__ s2,
                                               const float* __restrict__ q2,
                                               float* __restrict__ out) {
    __shared__ float yl[Tn * 33];
    int tid = threadIdx.x;
    int blk = blockIdx.x;
    int b = blk >> 12, c = blk & (Cn - 1);
    {
        uint2 v = ((const uint2*)(bufC + (size_t)(b * Cn + c) * PLANE))[tid];
        int t = tid >> 3, f0 = (tid & 7) * 4;
        yl[t * 33 + f0 + 0] = bflo(v.x);
        yl[t * 33 + f0 + 1] = bfhi(v.x);
        yl[t * 33 + f0 + 2] = bflo(v.y);
        yl[t * 33 + f0 + 3] = bfhi(v.y);
    }
    __syncthreads();
    int f = tid >> 3, tb = (tid & 7) * 4;
    const float invN = 1.0f / (float)(Cn * Tn);
    float mu = s2[b * Fn + f] * invN;
    float var = q2[b * Fn + f] * invN - mu * mu;
    float r = rsqrtf(var + 1e-5f);
    size_t base = ((size_t)(b * Fn + f) * Cn + c) * Tn + tb;
    float4 xv = *(const float4*)(x + base);
    float xx[4] = {xv.x, xv.y, xv.z, xv.w};
    float oo[4];
    #pragma unroll
    for (int j = 0; j < 4; ++j) {
        float y = yl[(tb + j) * 33 + f];
        float yn = fmaxf(0.f, (y - mu) * r);
        oo[j] = fmaxf(0.f, yn + xx[j]);
    }
    *(float4*)(out + base) = make_float4(oo[0], oo[1], oo[2], oo[3]);
}

extern "C" void kernel_launch(void* const* d_in, const int* in_sizes, int n_in,
                              void* d_out, int out_size, void* d_ws, size_t ws_size,
                              hipStream_t stream) {
    const float* x  = (const float*)d_in[0];
    const int*   ei = (const int*)d_in[1];
    const float* ew = (const float*)d_in[2];
    const float* W  = (const float*)d_in[3];
    const float* gb = (const float*)d_in[4];
    const float* cw = (const float*)d_in[5];
    const float* cb = (const float*)d_in[6];
    float* out = (float*)d_out;

    char* p = (char*)d_ws;
    auto alloc = [&](size_t bytes) {
        char* r = p;
        p += (bytes + 255) & ~(size_t)255;
        return r;
    };
    ushort* bufA = (ushort*)alloc(sizeof(ushort) * (size_t)Bn * Cn * PLANE);  // 32 MB
    ushort* bufB = (ushort*)alloc(sizeof(ushort) * (size_t)Bn * Cn * PLANE);  // 32 MB
    ushort* bufC = (ushort*)alloc(sizeof(ushort) * (size_t)Bn * Cn * PLANE);  // 32 MB
    float* deg  = (float*)alloc(sizeof(float) * Cn);
    int*   hist = (int*)alloc(sizeof(int) * Cn);
    int*   cnt  = (int*)alloc(sizeof(int) * Cn);
    int*   ptr  = (int*)alloc(sizeof(int) * (Cn + 1));
    int*   csrs = (int*)alloc(sizeof(int) * En);
    float* csrw = (float*)alloc(sizeof(float) * En);
    float* s1   = (float*)alloc(sizeof(float) * Bn * Fn);
    float* q1   = (float*)alloc(sizeof(float) * Bn * Fn);
    float* s2   = (float*)alloc(sizeof(float) * Bn * Fn);
    float* q2   = (float*)alloc(sizeof(float) * Bn * Fn);
    ushort* wfrag = (ushort*)alloc(sizeof(ushort) * 2 * 9 * 64 * 8);  // 18 KB
    if ((size_t)(p - (char*)d_ws) > ws_size) return;  // insufficient workspace

    k_init<<<Cn / 256, 256, 0, stream>>>(deg, hist, cnt, s1, q1, s2, q2, cw, wfrag);
    k_deg<<<En / 256, 256, 0, stream>>>(ei, ew, deg, hist);
    k_scan<<<1, 1024, 0, stream>>>(hist, ptr);
    k_fill<<<En / 256, 256, 0, stream>>>(ei, ew, deg, ptr, cnt, csrs, csrw);
    k_xlin<<<Bn * (Cn / 4), 256, 0, stream>>>(x, W, bufA);
    k_agg<<<Cn, 256, 0, stream>>>(bufA, deg, ptr, csrs, csrw, gb, bufB, s1, q1);
    k_convm<<<Bn * (Cn / 8), 256, 0, stream>>>(bufB, s1, q1, wfrag, cb, bufC, s2, q2);
    k_final<<<Bn * Cn, 256, 0, stream>>>(bufC, x, s2, q2, out);
}

// Round 13
// 158.223 us; speedup vs baseline: 1.2386x; 1.0156x over previous
//
#include <hip/hip_runtime.h>
#include <cstddef>

namespace {
constexpr int Bn = 4, Fn = 32, Cn = 4096, Tn = 32, En = 65536, Kw = 9;
constexpr int PLANE = Tn * Fn;   // 1024 elems per (b,c) plane
}

typedef __attribute__((ext_vector_type(8))) short bf16x8;
typedef __attribute__((ext_vector_type(4))) float f32x4;

static __device__ __forceinline__ unsigned short f2bf(float f) {
    unsigned int u = __float_as_uint(f);
    unsigned int r = (u + 0x7fffu + ((u >> 16) & 1u)) >> 16;
    return (unsigned short)r;
}
// unpack uint (2 bf16) -> 2 floats: lo = u<<16, hi = u & 0xffff0000
static __device__ __forceinline__ float bflo(unsigned u) { return __uint_as_float(u << 16); }
static __device__ __forceinline__ float bfhi(unsigned u) { return __uint_as_float(u & 0xffff0000u); }

// ---------------- init (deg=1, hist=cnt=0, stats=0) + conv-weight fragments ----------------
__global__ __launch_bounds__(256) void k_init(float* deg, int* hist, int* cnt,
                                              float* s1, float* q1, float* s2, float* q2,
                                              const float* __restrict__ cw,
                                              ushort* __restrict__ wfrag) {
    int i = blockIdx.x * 256 + threadIdx.x;
    if (i < Cn) { deg[i] = 1.0f; hist[i] = 0; cnt[i] = 0; }
    if (i < Bn * Fn) { s1[i] = 0.f; q1[i] = 0.f; s2[i] = 0.f; q2[i] = 0.f; }
    if (i < 2 * 9 * 64) {
        int l  = i & 63;
        int k  = (i >> 6) % 9;
        int nt = i / 576;
        int o  = nt * 16 + (l & 15);
        int ib = (l >> 4) * 8;
        ushort v[8];
        #pragma unroll
        for (int j = 0; j < 8; ++j) v[j] = f2bf(cw[o * 288 + (ib + j) * 9 + k]);
        uint4 pk;
        pk.x = (unsigned)v[0] | ((unsigned)v[1] << 16);
        pk.y = (unsigned)v[2] | ((unsigned)v[3] << 16);
        pk.z = (unsigned)v[4] | ((unsigned)v[5] << 16);
        pk.w = (unsigned)v[6] | ((unsigned)v[7] << 16);
        ((uint4*)wfrag)[i] = pk;
    }
}

// ---------------- degree + dst histogram ----------------
__global__ __launch_bounds__(256) void k_deg(const int* ei, const float* ew, float* deg, int* hist) {
    int e = blockIdx.x * 256 + threadIdx.x;
    int d = ei[En + e];
    atomicAdd(&deg[d], ew[e]);
    atomicAdd(&hist[d], 1);
}

// ---------------- exclusive scan of hist (C=4096, one block) ----------------
__global__ __launch_bounds__(1024) void k_scan(const int* hist, int* ptr) {
    __shared__ int part[1024];
    int tid = threadIdx.x;
    int v0 = hist[tid*4+0], v1 = hist[tid*4+1], v2 = hist[tid*4+2], v3 = hist[tid*4+3];
    int tot = v0 + v1 + v2 + v3;
    part[tid] = tot;
    __syncthreads();
    for (int off = 1; off < 1024; off <<= 1) {
        int add = (tid >= off) ? part[tid - off] : 0;
        __syncthreads();
        part[tid] += add;
        __syncthreads();
    }
    int run = part[tid] - tot;  // exclusive base
    ptr[tid*4+0] = run; run += v0;
    ptr[tid*4+1] = run; run += v1;
    ptr[tid*4+2] = run; run += v2;
    ptr[tid*4+3] = run; run += v3;
    if (tid == 1023) ptr[4096] = run;
}

// ---------------- CSR fill (sorted by dst) with fused norm ----------------
__global__ __launch_bounds__(256) void k_fill(const int* ei, const float* ew, const float* deg,
                                              const int* ptr, int* cnt, int* csrs, float* csrw) {
    int e = blockIdx.x * 256 + threadIdx.x;
    int s = ei[e];
    int d = ei[En + e];
    float w = rsqrtf(deg[s]) * ew[e] * rsqrtf(deg[d]);
    int pos = ptr[d] + atomicAdd(&cnt[d], 1);
    csrs[pos] = s;
    csrw[pos] = w;
}

// ---------------- x_lin via MFMA: bufA[b][c][t][g] (bf16) = sum_f x[b,f,c,t]*W[f,g] ----------------
__global__ __launch_bounds__(256) void k_xlin(const float* __restrict__ x,
                                              const float* __restrict__ W,
                                              ushort* __restrict__ bufA) {
    int tid = threadIdx.x;
    int l = tid & 63, w = tid >> 6;
    int b = blockIdx.x >> 10;                  // 1024 blocks per b
    int c = (blockIdx.x & 1023) * 4 + w;       // one plane per wave
    int row = l & 15, kg = l >> 4;             // A row (t), k-group (f block)

    // B fragments: B[f=kg*8+j][g=row (+16)]
    bf16x8 wf0, wf1;
    #pragma unroll
    for (int j = 0; j < 8; ++j) {
        wf0[j] = (short)f2bf(W[(kg * 8 + j) * Fn + row]);
        wf1[j] = (short)f2bf(W[(kg * 8 + j) * Fn + 16 + row]);
    }

    // A fragments: A[t=row(+16)][f=kg*8+j] = x[b][f][c][t]
    const float* xp = x + ((size_t)(b * Fn) * Cn + c) * Tn;
    bf16x8 a0, a1;
    #pragma unroll
    for (int j = 0; j < 8; ++j) {
        size_t fo = (size_t)(kg * 8 + j) * Cn * Tn;
        a0[j] = (short)f2bf(xp[fo + row]);
        a1[j] = (short)f2bf(xp[fo + 16 + row]);
    }

    f32x4 d00 = {0,0,0,0}, d01 = {0,0,0,0}, d10 = {0,0,0,0}, d11 = {0,0,0,0};
    d00 = __builtin_amdgcn_mfma_f32_16x16x32_bf16(a0, wf0, d00, 0, 0, 0);
    d01 = __builtin_amdgcn_mfma_f32_16x16x32_bf16(a0, wf1, d01, 0, 0, 0);
    d10 = __builtin_amdgcn_mfma_f32_16x16x32_bf16(a1, wf0, d10, 0, 0, 0);
    d11 = __builtin_amdgcn_mfma_f32_16x16x32_bf16(a1, wf1, d11, 0, 0, 0);

    // D layout: col = l&15 (g), row = (l>>4)*4 + r (t)
    ushort* op = bufA + (size_t)(b * Cn + c) * PLANE;
    int col = l & 15, r0 = (l >> 4) * 4;
    #pragma unroll
    for (int r = 0; r < 4; ++r) {
        op[(r0 + r) * Fn + col]           = f2bf(d00[r]);
        op[(r0 + r) * Fn + 16 + col]      = f2bf(d01[r]);
        op[(16 + r0 + r) * Fn + col]      = f2bf(d10[r]);
        op[(16 + r0 + r) * Fn + 16 + col] = f2bf(d11[r]);
    }
}

// ---------------- GCN aggregation, XCD-L2-tiled SpMM, 16-deep gather pipeline ----------------
// Round-11 structure + 16-deep unroll (halves group-boundary stalls) and
// carried ptr (j1 of node c becomes j0 of node c+1 without a reload).
__global__ __launch_bounds__(256) void k_agg(const ushort* __restrict__ bufA,
                                             const float* __restrict__ deg,
                                             const int* __restrict__ ptr,
                                             const int* __restrict__ csrs,
                                             const float* __restrict__ csrw,
                                             const float* __restrict__ gb,
                                             ushort* __restrict__ bufB,
                                             float* s1, float* q1) {
    __shared__ float ssum[Fn], ssq[Fn];
    int tid = threadIdx.x;
    int tile = blockIdx.x & 7;
    int chunk = blockIdx.x >> 3;          // 512 chunks
    int b = tile >> 1, half = tile & 1;
    int c0 = chunk * 8;
    if (tid < Fn) { ssum[tid] = 0.f; ssq[tid] = 0.f; }

    const ushort* base = bufA + (size_t)b * Cn * PLANE + half * 512;
    ushort* obase = bufB + (size_t)b * Cn * PLANE + half * 512;
    int e0 = tid * 2;                      // elem pair within the 512-slice
    int f0 = e0 & 31;                      // even f
    float g0 = gb[f0], g1 = gb[f0 + 1];

    float st0 = 0.f, st1 = 0.f, sq0 = 0.f, sq1 = 0.f;
    int jnext = ptr[c0];                   // carried row pointer
    for (int cc = 0; cc < 8; ++cc) {
        int c = c0 + cc;
        float d2 = 1.0f / deg[c];
        unsigned sv = *(const unsigned*)(base + (size_t)c * PLANE + e0);
        float ax = bflo(sv) * d2, ay = bfhi(sv) * d2;

        int j0 = jnext, j1 = ptr[c + 1];
        jnext = j1;
        int j = j0;
        for (; j + 15 < j1; j += 16) {
            int s[16]; float w[16]; unsigned u[16];
            #pragma unroll
            for (int i = 0; i < 16; ++i) { s[i] = csrs[j + i]; w[i] = csrw[j + i]; }
            #pragma unroll
            for (int i = 0; i < 16; ++i)
                u[i] = *(const unsigned*)(base + (size_t)s[i] * PLANE + e0);
            #pragma unroll
            for (int i = 0; i < 16; ++i) {
                ax += bflo(u[i]) * w[i];
                ay += bfhi(u[i]) * w[i];
            }
        }
        if (j + 7 < j1) {
            int s[8]; float w[8]; unsigned u[8];
            #pragma unroll
            for (int i = 0; i < 8; ++i) { s[i] = csrs[j + i]; w[i] = csrw[j + i]; }
            #pragma unroll
            for (int i = 0; i < 8; ++i)
                u[i] = *(const unsigned*)(base + (size_t)s[i] * PLANE + e0);
            #pragma unroll
            for (int i = 0; i < 8; ++i) {
                ax += bflo(u[i]) * w[i];
                ay += bfhi(u[i]) * w[i];
            }
            j += 8;
        }
        if (j + 3 < j1) {
            int s[4]; float w[4]; unsigned u[4];
            #pragma unroll
            for (int i = 0; i < 4; ++i) { s[i] = csrs[j + i]; w[i] = csrw[j + i]; }
            #pragma unroll
            for (int i = 0; i < 4; ++i)
                u[i] = *(const unsigned*)(base + (size_t)s[i] * PLANE + e0);
            #pragma unroll
            for (int i = 0; i < 4; ++i) {
                ax += bflo(u[i]) * w[i];
                ay += bfhi(u[i]) * w[i];
            }
            j += 4;
        }
        for (; j < j1; ++j) {
            int s0 = csrs[j];
            float w0 = csrw[j];
            unsigned u0 = *(const unsigned*)(base + (size_t)s0 * PLANE + e0);
            ax += bflo(u0) * w0; ay += bfhi(u0) * w0;
        }
        ax += g0; ay += g1;
        unsigned pk = (unsigned)f2bf(ax) | ((unsigned)f2bf(ay) << 16);
        __builtin_nontemporal_store(pk, (unsigned*)(obase + (size_t)c * PLANE + e0));
        st0 += ax; sq0 += ax * ax; st1 += ay; sq1 += ay * ay;
    }

    // lanes l, l+16, l+32, l+48 share f -> shfl reduce, then LDS atomics
    st0 += __shfl_xor(st0, 16); st0 += __shfl_xor(st0, 32);
    sq0 += __shfl_xor(sq0, 16); sq0 += __shfl_xor(sq0, 32);
    st1 += __shfl_xor(st1, 16); st1 += __shfl_xor(st1, 32);
    sq1 += __shfl_xor(sq1, 16); sq1 += __shfl_xor(sq1, 32);
    __syncthreads();  // ssum/ssq zeroed
    if ((tid & 63) < 16) {
        int l = tid & 15;
        atomicAdd(&ssum[2*l],     st0); atomicAdd(&ssq[2*l],     sq0);
        atomicAdd(&ssum[2*l + 1], st1); atomicAdd(&ssq[2*l + 1], sq1);
    }
    __syncthreads();
    if (tid < Fn) {
        atomicAdd(&s1[b * Fn + tid], ssum[tid]);
        atomicAdd(&q1[b * Fn + tid], ssq[tid]);
    }
}

// ---------------- IN1 -> ReLU -> Conv(1xK) via bf16 MFMA + IN2 stats ----------------
__global__ __launch_bounds__(256) void k_convm(const ushort* __restrict__ bufB,
                                               const float* __restrict__ s1,
                                               const float* __restrict__ q1,
                                               const ushort* __restrict__ wfrag,
                                               const float* __restrict__ cb,
                                               ushort* __restrict__ bufC,
                                               float* s2, float* q2) {
    __shared__ __align__(16) ushort zbuf[4 * 40 * 72];
    __shared__ float ssum[Fn], ssq[Fn];
    int tid = threadIdx.x;
    int l = tid & 63, w = tid >> 6;
    int b  = blockIdx.x >> 9;                 // 512 blocks per b
    int c0 = (blockIdx.x & 511) * 8 + w * 2;  // 2 planes per wave

    if (tid < Fn) { ssum[tid] = 0.f; ssq[tid] = 0.f; }

    ushort* z = zbuf + w * (40 * 72);
    if (l < 16) {  // zero pad rows 0..3 and 36..39, cols 0..31 (only ones read)
        #pragma unroll
        for (int p = 0; p < 4; ++p) {
            *(unsigned*)&z[p * 72 + l * 2] = 0u;
            *(unsigned*)&z[(36 + p) * 72 + l * 2] = 0u;
        }
    }

    // B fragments resident in VGPRs
    bf16x8 wf0[9], wf1[9];
    #pragma unroll
    for (int k = 0; k < Kw; ++k) {
        wf0[k] = *(const bf16x8*)(wfrag + ((0 * 9 + k) * 64 + l) * 8);
        wf1[k] = *(const bf16x8*)(wfrag + ((1 * 9 + k) * 64 + l) * 8);
    }
    // IN1 finalize inline: f = (l&1)*16 + j ; pm = -mu*r, pr = r
    const float invN = 1.0f / (float)(Cn * Tn);
    float pm[16], pr[16];
    {
        int fb = b * Fn + (l & 1) * 16;
        #pragma unroll
        for (int j = 0; j < 16; ++j) {
            float mu = s1[fb + j] * invN;
            float var = q1[fb + j] * invN - mu * mu;
            float r = rsqrtf(var + 1e-5f);
            pm[j] = -mu * r; pr[j] = r;
        }
    }
    float cbv0 = cb[l & 15], cbv1 = cb[16 + (l & 15)];
    __syncthreads();

    float ss0 = 0.f, ss1 = 0.f, qq0 = 0.f, qq1 = 0.f;
    const ushort* za = z + (l & 15) * 72 + (l >> 4) * 8;

    for (int p = 0; p < 2; ++p) {
        int c = c0 + p;
        // ---- build z: load bf16 plane, IN1-normalize + ReLU, back to bf16 ----
        const ushort* src = bufB + (size_t)(b * Cn + c) * PLANE + l * 16;
        uint4 i0 = *(const uint4*)(src);
        uint4 i1 = *(const uint4*)(src + 8);
        float iv[16] = { bflo(i0.x), bfhi(i0.x), bflo(i0.y), bfhi(i0.y),
                         bflo(i0.z), bfhi(i0.z), bflo(i0.w), bfhi(i0.w),
                         bflo(i1.x), bfhi(i1.x), bflo(i1.y), bfhi(i1.y),
                         bflo(i1.z), bfhi(i1.z), bflo(i1.w), bfhi(i1.w) };
        ushort tmp[16];
        #pragma unroll
        for (int j = 0; j < 16; ++j)
            tmp[j] = f2bf(fmaxf(0.f, iv[j] * pr[j] + pm[j]));
        {
            int t = l >> 1, h = l & 1;
            ushort* zw = z + (t + 4) * 72 + h * 16;
            uint4 w0, w1;
            w0.x = (unsigned)tmp[0] | ((unsigned)tmp[1] << 16);
            w0.y = (unsigned)tmp[2] | ((unsigned)tmp[3] << 16);
            w0.z = (unsigned)tmp[4] | ((unsigned)tmp[5] << 16);
            w0.w = (unsigned)tmp[6] | ((unsigned)tmp[7] << 16);
            w1.x = (unsigned)tmp[8] | ((unsigned)tmp[9] << 16);
            w1.y = (unsigned)tmp[10] | ((unsigned)tmp[11] << 16);
            w1.z = (unsigned)tmp[12] | ((unsigned)tmp[13] << 16);
            w1.w = (unsigned)tmp[14] | ((unsigned)tmp[15] << 16);
            *(uint4*)(zw) = w0;
            *(uint4*)(zw + 8) = w1;
        }
        // same-wave LDS write->read dependency: compiler inserts lgkmcnt waits

        // ---- MFMA: D[32t x 32o] = A[32t x 288] * B[288 x 32o] ----
        f32x4 acc00 = {0,0,0,0}, acc01 = {0,0,0,0}, acc10 = {0,0,0,0}, acc11 = {0,0,0,0};
        #pragma unroll
        for (int k = 0; k < Kw; ++k) {
            bf16x8 a0 = *(const bf16x8*)(za + k * 72);
            acc00 = __builtin_amdgcn_mfma_f32_16x16x32_bf16(a0, wf0[k], acc00, 0, 0, 0);
            acc01 = __builtin_amdgcn_mfma_f32_16x16x32_bf16(a0, wf1[k], acc01, 0, 0, 0);
        }
        #pragma unroll
        for (int k = 0; k < Kw; ++k) {
            bf16x8 a1 = *(const bf16x8*)(za + (16 + k) * 72);
            acc10 = __builtin_amdgcn_mfma_f32_16x16x32_bf16(a1, wf0[k], acc10, 0, 0, 0);
            acc11 = __builtin_amdgcn_mfma_f32_16x16x32_bf16(a1, wf1[k], acc11, 0, 0, 0);
        }

        // ---- epilogue: +bias, store bf16, IN2 partial stats (fp32) ----
        ushort* dst = bufC + (size_t)(b * Cn + c) * PLANE;
        int col = l & 15, r0 = (l >> 4) * 4;
        #pragma unroll
        for (int r = 0; r < 4; ++r) {
            float v00 = acc00[r] + cbv0;
            float v01 = acc01[r] + cbv1;
            float v10 = acc10[r] + cbv0;
            float v11 = acc11[r] + cbv1;
            dst[(r0 + r) * 32 + col]            = f2bf(v00);
            dst[(r0 + r) * 32 + 16 + col]       = f2bf(v01);
            dst[(16 + r0 + r) * 32 + col]       = f2bf(v10);
            dst[(16 + r0 + r) * 32 + 16 + col]  = f2bf(v11);
            ss0 += v00 + v10; qq0 += v00 * v00 + v10 * v10;
            ss1 += v01 + v11; qq1 += v01 * v01 + v11 * v11;
        }
    }

    // ---- reduce stats across the 4 lane-groups, accumulate to block LDS ----
    ss0 += __shfl_xor(ss0, 16); ss0 += __shfl_xor(ss0, 32);
    qq0 += __shfl_xor(qq0, 16); qq0 += __shfl_xor(qq0, 32);
    ss1 += __shfl_xor(ss1, 16); ss1 += __shfl_xor(ss1, 32);
    qq1 += __shfl_xor(qq1, 16); qq1 += __shfl_xor(qq1, 32);
    if ((l >> 4) == 0) {
        atomicAdd(&ssum[l], ss0);      atomicAdd(&ssq[l], qq0);
        atomicAdd(&ssum[16 + l], ss1); atomicAdd(&ssq[16 + l], qq1);
    }
    __syncthreads();
    if (tid < Fn) {
        atomicAdd(&s2[b * Fn + tid], ssum[tid]);
        atomicAdd(&q2[b * Fn + tid], ssq[tid]);
    }
}

// ---------------- IN2 -> ReLU -> +x -> ReLU, transpose to [b][f][c][t] ----------------
__global__ __launch_bounds__(256) void k_final(const ushort* __restrict__ bufC,
                                               const float* __restrict__ x,
                                               const float* __restrict__ s2,
                                               const float* __restrict__ q2,
                                               float* __restrict__ out) {
    __shared__ float yl[Tn * 33];
    int tid = threadIdx.x;
    int blk = blockIdx.x;
    int b = blk >> 12, c = blk & (Cn - 1);
    {
        uint2 v = ((const uint2*)(bufC + (size_t)(b * Cn + c) * PLANE))[tid];
        int t = tid >> 3, f0 = (tid & 7) * 4;
        yl[t * 33 + f0 + 0] = bflo(v.x);
        yl[t * 33 + f0 + 1] = bfhi(v.x);
        yl[t * 33 + f0 + 2] = bflo(v.y);
        yl[t * 33 + f0 + 3] = bfhi(v.y);
    }
    __syncthreads();
    int f = tid >> 3, tb = (tid & 7) * 4;
    const float invN = 1.0f / (float)(Cn * Tn);
    float mu = s2[b * Fn + f] * invN;
    float var = q2[b * Fn + f] * invN - mu * mu;
    float r = rsqrtf(var + 1e-5f);
    size_t base = ((size_t)(b * Fn + f) * Cn + c) * Tn + tb;
    float4 xv = *(const float4*)(x + base);
    float xx[4] = {xv.x, xv.y, xv.z, xv.w};
    float oo[4];
    #pragma unroll
    for (int j = 0; j < 4; ++j) {
        float y = yl[(tb + j) * 33 + f];
        float yn = fmaxf(0.f, (y - mu) * r);
        oo[j] = fmaxf(0.f, yn + xx[j]);
    }
    *(float4*)(out + base) = make_float4(oo[0], oo[1], oo[2], oo[3]);
}

extern "C" void kernel_launch(void* const* d_in, const int* in_sizes, int n_in,
                              void* d_out, int out_size, void* d_ws, size_t ws_size,
                              hipStream_t stream) {
    const float* x  = (const float*)d_in[0];
    const int*   ei = (const int*)d_in[1];
    const float* ew = (const float*)d_in[2];
    const float* W  = (const float*)d_in[3];
    const float* gb = (const float*)d_in[4];
    const float* cw = (const float*)d_in[5];
    const float* cb = (const float*)d_in[6];
    float* out = (float*)d_out;

    char* p = (char*)d_ws;
    auto alloc = [&](size_t bytes) {
        char* r = p;
        p += (bytes + 255) & ~(size_t)255;
        return r;
    };
    ushort* bufA = (ushort*)alloc(sizeof(ushort) * (size_t)Bn * Cn * PLANE);  // 32 MB
    ushort* bufB = (ushort*)alloc(sizeof(ushort) * (size_t)Bn * Cn * PLANE);  // 32 MB
    ushort* bufC = (ushort*)alloc(sizeof(ushort) * (size_t)Bn * Cn * PLANE);  // 32 MB
    float* deg  = (float*)alloc(sizeof(float) * Cn);
    int*   hist = (int*)alloc(sizeof(int) * Cn);
    int*   cnt  = (int*)alloc(sizeof(int) * Cn);
    int*   ptr  = (int*)alloc(sizeof(int) * (Cn + 1));
    int*   csrs = (int*)alloc(sizeof(int) * En);
    float* csrw = (float*)alloc(sizeof(float) * En);
    float* s1   = (float*)alloc(sizeof(float) * Bn * Fn);
    float* q1   = (float*)alloc(sizeof(float) * Bn * Fn);
    float* s2   = (float*)alloc(sizeof(float) * Bn * Fn);
    float* q2   = (float*)alloc(sizeof(float) * Bn * Fn);
    ushort* wfrag = (ushort*)alloc(sizeof(ushort) * 2 * 9 * 64 * 8);  // 18 KB
    if ((size_t)(p - (char*)d_ws) > ws_size) return;  // insufficient workspace

    k_init<<<Cn / 256, 256, 0, stream>>>(deg, hist, cnt, s1, q1, s2, q2, cw, wfrag);
    k_deg<<<En / 256, 256, 0, stream>>>(ei, ew, deg, hist);
    k_scan<<<1, 1024, 0, stream>>>(hist, ptr);
    k_fill<<<En / 256, 256, 0, stream>>>(ei, ew, deg, ptr, cnt, csrs, csrw);
    k_xlin<<<Bn * (Cn / 4), 256, 0, stream>>>(x, W, bufA);
    k_agg<<<Cn, 256, 0, stream>>>(bufA, deg, ptr, csrs, csrw, gb, bufB, s1, q1);
    k_convm<<<Bn * (Cn / 8), 256, 0, stream>>>(bufB, s1, q1, wfrag, cb, bufC, s2, q2);
    k_final<<<Bn * Cn, 256, 0, stream>>>(bufC, x, s2, q2, out);
}